// Round 8
// baseline (21.898 us; speedup 1.0000x reference)
//
#include <hip/hip_runtime.h>

// GMP: y[b,s] = sum_{l=0}^{9} C_l(b,s) * x[b,s-l], zero for s < 20.
// C_l = sum_{k=0}^{3} a[k, 9-l] |x[s-l]|^k
//     + sum_{m=0}^{9} sum_{k=1}^{4} b[k-1,l,m] |x[s-l-1-m]|^k
// All fp32. Input c unused by the reference.
//
// Round-8: coefficients delivered via the SCALAR pipe instead of LDS
// broadcasts (round-6's dominant cost: 110 ds_read_b128/wave ~= 10us of
// LDS return BW, irreducible while per-lane replicated). A prep kernel
// packs a,b into d_ws k-contiguous (44 floats per l, 16B aligned); the
// main kernel has NO LDS and NO barrier, so uniform-address float4
// coefficient loads convert to s_load (SMEM) and feed FMAs as SGPR
// operands. x window read from global (L1-resident, clamped aligned
// loads; clamp garbage only reaches force-masked s<20 outputs).

constexpr int Lp = 10;
constexpr int Mp = 10;
constexpr int Dp = Lp + Mp;        // 20
constexpr int BLK = 256;
constexpr int T = 2;               // samples per thread
constexpr int TILE = BLK * T;      // 512 samples per block
constexpr int S_FIXED = 16384;
constexpr int PACKN = Lp * 44;     // 440 floats

// pack[l*44 + 0..3]        = a[k][9-l]           (k = 0..3)
// pack[l*44 + 4 + 4m + k]  = b[k][l][m]
__global__ void gmp_pack(const float* __restrict__ a,
                         const float* __restrict__ b,
                         float* __restrict__ pk) {
    const int i = threadIdx.x;
    if (i < PACKN) {
        const int l = i / 44, r = i % 44;
        float v;
        if (r < 4) v = a[r * Lp + (Lp - 1 - l)];
        else {
            const int k = (r - 4) & 3, m = (r - 4) >> 2;
            v = b[k * Lp * Mp + l * Mp + m];
        }
        pk[i] = v;
    }
}

__global__ __launch_bounds__(BLK) void gmp_kernel(
    const float* __restrict__ x,   // (B, S, 2)
    const float* __restrict__ pk,  // packed coefficients (440)
    float* __restrict__ out,       // (B, S, 2)
    int S)
{
    const int t = threadIdx.x;
    const int blocksPerRow = S / TILE;     // 32
    const int brow = blockIdx.x / blocksPerRow;
    const int s0   = (blockIdx.x % blocksPerRow) * TILE;
    const int sA   = s0 + 2 * t;           // first of this thread's 2 samples

    const float* xrow = x + (size_t)brow * S * 2;
    const float4* __restrict__ xr4 = reinterpret_cast<const float4*>(xrow);
    const float2* __restrict__ xr2 = reinterpret_cast<const float2*>(xrow);
    const float4* __restrict__ pk4 = reinterpret_cast<const float4*>(pk);

    // Window position w (0..20) <-> complex sample p = sA + w - 19.
    // a-part (sample j, delay l): w = 19+j-l;  b-part: w = 18+j-l-m.
    float q1[21], q2[21], q3[21], q4[21];  // <=12 positions live at a time
    float rex[11], imx[11];                // re/im of w = r+10

#define GMP_QUAD(i, vx, vy)                                   \
    {                                                         \
        const float m2_ = (vx) * (vx) + (vy) * (vy);          \
        const float r_  = __builtin_amdgcn_sqrtf(m2_);        \
        q1[(i)] = r_;  q2[(i)] = m2_;                         \
        q3[(i)] = m2_ * r_;  q4[(i)] = m2_ * m2_;             \
    }

    // init: w in [9,21) -> p in [sA-10, sA+2), 24 floats = 6 aligned float4
    // float4 index = (sA-10)/2 + n (sA even, s0 mult. of 512 -> integer).
    {
        const int i4base = (sA - 10) / 2;
        #pragma unroll
        for (int n = 0; n < 6; ++n) {
            int idx = i4base + n;
            if (idx < 0) idx = 0;          // garbage -> masked outputs only
            const float4 f = xr4[idx];
            const int w0 = 9 + 2 * n, w1 = 10 + 2 * n;
            GMP_QUAD(w0, f.x, f.y);
            GMP_QUAD(w1, f.z, f.w);
            if (w0 >= 10) { rex[w0 - 10] = f.x; imx[w0 - 10] = f.y; }
            rex[w1 - 10] = f.z; imx[w1 - 10] = f.w;
        }
    }

    float yr0 = 0.f, yi0 = 0.f, yr1 = 0.f, yi1 = 0.f;

    #pragma unroll
    for (int l = 0; l < Lp; ++l) {
        if (l > 0) {                       // roll: add quad at w = 9-l
            int p = sA - 10 - l;
            if (p < 0) p = 0;              // masked-output garbage only
            const float2 nv = xr2[p];
            GMP_QUAD(9 - l, nv.x, nv.y);
        }
        const float4 ac = pk4[l * 11];     // uniform -> s_load
        const int wa0 = 19 - l, wa1 = 20 - l;
        float C0 = ac.x + ac.y * q1[wa0] + ac.z * q2[wa0] + ac.w * q3[wa0];
        float C1 = ac.x + ac.y * q1[wa1] + ac.z * q2[wa1] + ac.w * q3[wa1];
        #pragma unroll
        for (int m = 0; m < Mp; ++m) {
            const float4 bc = pk4[l * 11 + 1 + m];   // uniform -> s_load
            const int w0 = 18 - l - m, w1 = 19 - l - m;
            C0 += bc.x * q1[w0] + bc.y * q2[w0] + bc.z * q3[w0] + bc.w * q4[w0];
            C1 += bc.x * q1[w1] + bc.y * q2[w1] + bc.z * q3[w1] + bc.w * q4[w1];
        }
        const int r = 9 - l;
        yr0 += C0 * rex[r];     yi0 += C0 * imx[r];
        yr1 += C1 * rex[r + 1]; yi1 += C1 * imx[r + 1];
    }
#undef GMP_QUAD

    // masked store: 2 consecutive float2 = 1 float4 store
    const bool k0 = (sA + 0) >= Dp, k1 = (sA + 1) >= Dp;
    const float4 o = make_float4(k0 ? yr0 : 0.f, k0 ? yi0 : 0.f,
                                 k1 ? yr1 : 0.f, k1 ? yi1 : 0.f);
    reinterpret_cast<float4*>(out)[((size_t)brow * S + sA) / 2] = o;
}

extern "C" void kernel_launch(void* const* d_in, const int* in_sizes, int n_in,
                              void* d_out, int out_size, void* d_ws, size_t ws_size,
                              hipStream_t stream) {
    const float* x = (const float*)d_in[0];
    const float* a = (const float*)d_in[1];
    const float* b = (const float*)d_in[2];
    // d_in[3] (c) is unused by the reference.
    float* out = (float*)d_out;
    float* pk  = (float*)d_ws;             // 440 floats of scratch

    const int S = S_FIXED;
    const int B = in_sizes[0] / (2 * S);
    const int nblocks = B * (S / TILE);

    gmp_pack<<<dim3(1), dim3(512), 0, stream>>>(a, b, pk);
    gmp_kernel<<<dim3(nblocks), dim3(BLK), 0, stream>>>(x, pk, out, S);
}